// Round 1
// baseline (805.588 us; speedup 1.0000x reference)
//
#include <hip/hip_runtime.h>
#include <hip/hip_bf16.h>

// ReLU on 16384x8192 fp32. Pure memory-bound streaming kernel:
// float4 (16B/lane) coalesced loads/stores, one element-group per thread.

__global__ __launch_bounds__(256) void relu_f32x4_kernel(
    const float4* __restrict__ in, float4* __restrict__ out, long long n4) {
  long long i = (long long)blockIdx.x * blockDim.x + threadIdx.x;
  if (i < n4) {
    float4 v = in[i];
    v.x = fmaxf(v.x, 0.0f);
    v.y = fmaxf(v.y, 0.0f);
    v.z = fmaxf(v.z, 0.0f);
    v.w = fmaxf(v.w, 0.0f);
    out[i] = v;
  }
}

__global__ void relu_f32_tail_kernel(
    const float* __restrict__ in, float* __restrict__ out,
    long long start, long long n) {
  long long i = start + (long long)blockIdx.x * blockDim.x + threadIdx.x;
  if (i < n) {
    out[i] = fmaxf(in[i], 0.0f);
  }
}

extern "C" void kernel_launch(void* const* d_in, const int* in_sizes, int n_in,
                              void* d_out, int out_size, void* d_ws, size_t ws_size,
                              hipStream_t stream) {
  const float* in = (const float*)d_in[0];
  float* out = (float*)d_out;
  long long n = (long long)in_sizes[0];  // 134,217,728
  long long n4 = n / 4;                  // 33,554,432 float4s

  const int block = 256;
  long long grid = (n4 + block - 1) / block;  // 131072 blocks
  relu_f32x4_kernel<<<(unsigned)grid, block, 0, stream>>>(
      (const float4*)in, (float4*)out, n4);

  long long tail_start = n4 * 4;
  long long tail = n - tail_start;  // 0 for this shape, but stay correct
  if (tail > 0) {
    relu_f32_tail_kernel<<<1, 64, 0, stream>>>(in, out, tail_start, n);
  }
}